// Round 14
// baseline (366.359 us; speedup 1.0000x reference)
//
#include <hip/hip_runtime.h>
#include <cstdint>
#include <cstddef>

#define N_NODES 65536
#define N_EDGES 1048576
#define E_TOT   (N_EDGES + N_NODES)

using short8  = __attribute__((ext_vector_type(8))) short;
using floatx4 = __attribute__((ext_vector_type(4))) float;
using half8   = __attribute__((ext_vector_type(8))) _Float16;
using half4   = __attribute__((ext_vector_type(4))) _Float16;
typedef unsigned short ushort_t;
typedef unsigned long long u64;

// split fp32 -> bf16 hi (RTN) + bf16 lo (trunc of residual)
__device__ inline void split_bf16(float a, short& hi, short& lo) {
    unsigned u  = __float_as_uint(a);
    unsigned hr = (u + 0x7fffu + ((u >> 16) & 1u)) >> 16;
    float    hf = __uint_as_float(hr << 16);
    hi = (short)hr;
    float    lf = a - hf;
    lo = (short)(__float_as_uint(lf) >> 16);
}

// ---------------- preprocessing ----------------
// deg[] zeroed via hipMemsetAsync. Self-loop handled outside the edge stream.

// histogram + deterministic rank capture: ed2[e] = rank<<32 | (s<<16) | d
// 4 edges per thread: independent atomic round-trips overlap per thread.
__global__ void k_hist(const int* __restrict__ src, const int* __restrict__ dst,
                       int* __restrict__ deg, u64* __restrict__ ed2) {
    int base = blockIdx.x * 1024;
    #pragma unroll
    for (int j = 0; j < 4; ++j) {
        int e = base + j * 256 + threadIdx.x;
        if (e < N_EDGES) {
            int d = __builtin_nontemporal_load(&dst[e]);
            int s = __builtin_nontemporal_load(&src[e]);
            int rank = atomicAdd(&deg[d], 1);
            u64 rec = ((u64)(unsigned)rank << 32) | (u64)((unsigned)d | ((unsigned)s << 16));
            __builtin_nontemporal_store(rec, &ed2[e]);
        }
    }
}

__global__ __launch_bounds__(256) void k_scan1(const int* __restrict__ deg, int* __restrict__ off,
                                               int* __restrict__ bsum) {
    __shared__ int sb[256];
    int tid = threadIdx.x;
    int g = blockIdx.x * 256 + tid;
    int v = deg[g] + 1;               // +1: self loop
    sb[tid] = v;
    __syncthreads();
    #pragma unroll
    for (int s = 1; s < 256; s <<= 1) {
        int t = (tid >= s) ? sb[tid - s] : 0;
        __syncthreads();
        sb[tid] += t;
        __syncthreads();
    }
    off[g] = sb[tid] - v;
    if (tid == 255) bsum[blockIdx.x] = sb[255];
}

__global__ __launch_bounds__(256) void k_scan2(int* __restrict__ bsum) {
    __shared__ int sb[256];
    int tid = threadIdx.x;
    int v = bsum[tid];
    sb[tid] = v;
    __syncthreads();
    #pragma unroll
    for (int s = 1; s < 256; s <<= 1) {
        int t = (tid >= s) ? sb[tid - s] : 0;
        __syncthreads();
        sb[tid] += t;
        __syncthreads();
    }
    bsum[tid] = sb[tid] - v;
}

// finalize offsets, dis, and place the self-loop edge at the end of each segment
__global__ __launch_bounds__(256) void k_scan3(const int* __restrict__ deg, int* __restrict__ off,
                                               float* __restrict__ dis, const int* __restrict__ bsum,
                                               ushort_t* __restrict__ ssort) {
    int tid = threadIdx.x;
    int g = blockIdx.x * 256 + tid;
    int d = deg[g];
    int o = off[g] + bsum[blockIdx.x];
    off[g] = o;
    dis[g] = rsqrtf((float)(d + 1));        // +1: self loop
    ssort[o + d] = (ushort_t)g;             // self loop at segment end
    if (g == 0) off[N_NODES] = E_TOT;
}

// atomic-free scatter: slot = off[d] + rank (rank captured in k_hist)
__global__ void k_scatter(const u64* __restrict__ ed2, const int* __restrict__ off,
                          ushort_t* __restrict__ ssort) {
    int e = blockIdx.x * 256 + threadIdx.x;
    if (e >= N_EDGES) return;
    u64 v = __builtin_nontemporal_load(&ed2[e]);
    int d = (int)(v & 0xffffu);
    int s = (int)((v >> 16) & 0xffffu);
    int rank = (int)(v >> 32);
    ssort[off[d] + rank] = (ushort_t)s;
}

// ---------------- x -> fp16 rows pre-scaled by dis[row] ----------------

__global__ __launch_bounds__(256) void k_convx(const float* __restrict__ x, const float* __restrict__ dis,
                                               _Float16* __restrict__ xh) {
    int g = blockIdx.x * 256 + threadIdx.x;   // group of 4 elements
    int idx = g * 4;
    int row = idx >> 7;
    float d = dis[row];
    float4 v = *(const float4*)(x + idx);
    half4 o = {(_Float16)(d * v.x), (_Float16)(d * v.y), (_Float16)(d * v.z), (_Float16)(d * v.w)};
    *(half4*)(xh + idx) = o;
}

// ---------------- W1,W2,W3 -> fragment-ordered bf16 hi/lo (single launch) ----------------

__device__ inline void convw_one(const float* W, int K, int N, short* Bh, short* Bl, int g) {
    int lane = g & 63;
    int kt = (g >> 6) % (K / 32);
    int nt = (g >> 6) / (K / 32);
    int n = nt * 16 + (lane & 15);
    int kbase = kt * 32 + (lane >> 4) * 8;
    #pragma unroll
    for (int j = 0; j < 8; ++j) {
        short h, l;
        split_bf16(W[(size_t)(kbase + j) * N + n], h, l);
        Bh[(size_t)g * 8 + j] = h;
        Bl[(size_t)g * 8 + j] = l;
    }
}

#define G1 (16 * 4 * 64)   // W1 128x256
#define G2 (8 * 8 * 64)    // W2 256x128
#define G3 (4 * 4 * 64)    // W3 128x64

__global__ void k_convw3(const float* __restrict__ W1, short* __restrict__ w1h, short* __restrict__ w1l,
                         const float* __restrict__ W2, short* __restrict__ w2h, short* __restrict__ w2l,
                         const float* __restrict__ W3, short* __restrict__ w3h, short* __restrict__ w3l) {
    int g = blockIdx.x * 256 + threadIdx.x;
    if (g < G1)            convw_one(W1, 128, 256, w1h, w1l, g);
    else if (g < G1 + G2)  convw_one(W2, 256, 128, w2h, w2l, g - G1);
    else if (g < G1 + G2 + G3) convw_one(W3, 128, 64, w3h, w3l, g - G1 - G2);
}

// ---------------- split-bf16 MFMA GEMM: C[M,N] = A[M,K] @ W ----------------
// A is fp16 rows. ACT: C = softmax(relu(C + bias)) -> fp16.
// else: C = dis[row] * C -> fp16 (feeds the gather).

template <int K, int N, bool ACT>
__global__ __launch_bounds__(256) void k_mm(const _Float16* __restrict__ A,
                                            const short* __restrict__ Bh, const short* __restrict__ Bl,
                                            const float* __restrict__ bias, const float* __restrict__ dis,
                                            _Float16* __restrict__ Cout) {
    constexpr int NT = N / 16;
    constexpr int KT = K / 32;
    __shared__ short Ah[4 * 64 * 8];
    __shared__ short Al[4 * 64 * 8];
    int tid = threadIdx.x;
    int wave = tid >> 6, lane = tid & 63;
    int quad = lane >> 4, col = lane & 15;
    size_t row0 = (size_t)blockIdx.x * 64;

    floatx4 acc[NT];
    #pragma unroll
    for (int t = 0; t < NT; ++t) acc[t] = (floatx4)0.0f;

    int srow = tid >> 2;
    int sdst = ((srow >> 4) * 64 + (srow & 15) + ((tid & 3) << 4)) * 8;
    const _Float16* arow = A + (row0 + srow) * K + (tid & 3) * 8;

    for (int kt = 0; kt < KT; ++kt) {
        half8 a8 = *(const half8*)(arow + kt * 32);
        short h[8], l[8];
        #pragma unroll
        for (int j = 0; j < 8; ++j) split_bf16((float)a8[j], h[j], l[j]);
        __syncthreads();
        *(short8*)(&Ah[sdst]) = *(short8*)h;
        *(short8*)(&Al[sdst]) = *(short8*)l;
        __syncthreads();
        short8 afh = *(short8*)(&Ah[(wave * 64 + lane) * 8]);
        short8 afl = *(short8*)(&Al[(wave * 64 + lane) * 8]);
        #pragma unroll
        for (int nt = 0; nt < NT; ++nt) {
            size_t bi = ((size_t)(nt * KT + kt) * 64 + lane);
            short8 bfh = ((const short8*)Bh)[bi];
            short8 bfl = ((const short8*)Bl)[bi];
            acc[nt] = __builtin_amdgcn_mfma_f32_16x16x32_bf16(afh, bfh, acc[nt], 0, 0, 0);
            acc[nt] = __builtin_amdgcn_mfma_f32_16x16x32_bf16(afh, bfl, acc[nt], 0, 0, 0);
            acc[nt] = __builtin_amdgcn_mfma_f32_16x16x32_bf16(afl, bfh, acc[nt], 0, 0, 0);
        }
    }

    size_t rbase = row0 + wave * 16 + quad * 4;
    if (!ACT) {
        float4 d4 = *(const float4*)(dis + rbase);
        float dr[4] = {d4.x, d4.y, d4.z, d4.w};
        #pragma unroll
        for (int nt = 0; nt < NT; ++nt)
            #pragma unroll
            for (int r = 0; r < 4; ++r)
                Cout[(rbase + r) * N + nt * 16 + col] = (_Float16)(acc[nt][r] * dr[r]);
    } else {
        float bv[NT];
        #pragma unroll
        for (int nt = 0; nt < NT; ++nt) bv[nt] = bias[nt * 16 + col];
        float mr[4] = {0.f, 0.f, 0.f, 0.f};
        #pragma unroll
        for (int nt = 0; nt < NT; ++nt)
            #pragma unroll
            for (int r = 0; r < 4; ++r) {
                float v = fmaxf(acc[nt][r] + bv[nt], 0.0f);
                acc[nt][r] = v;
                mr[r] = fmaxf(mr[r], v);
            }
        #pragma unroll
        for (int mask = 1; mask < 16; mask <<= 1)
            #pragma unroll
            for (int r = 0; r < 4; ++r) mr[r] = fmaxf(mr[r], __shfl_xor(mr[r], mask, 64));
        float sr[4] = {0.f, 0.f, 0.f, 0.f};
        #pragma unroll
        for (int nt = 0; nt < NT; ++nt)
            #pragma unroll
            for (int r = 0; r < 4; ++r) {
                float t = __expf(acc[nt][r] - mr[r]);
                acc[nt][r] = t;
                sr[r] += t;
            }
        #pragma unroll
        for (int mask = 1; mask < 16; mask <<= 1)
            #pragma unroll
            for (int r = 0; r < 4; ++r) sr[r] += __shfl_xor(sr[r], mask, 64);
        float inv[4];
        #pragma unroll
        for (int r = 0; r < 4; ++r) inv[r] = 1.0f / sr[r];
        #pragma unroll
        for (int nt = 0; nt < NT; ++nt)
            #pragma unroll
            for (int r = 0; r < 4; ++r)
                Cout[(rbase + r) * N + nt * 16 + col] = (_Float16)(acc[nt][r] * inv[r]);
    }
}

// ---------------- aggregation, DOUT=128, fp16 rows: quarter-wave (16 lanes x 16B) per edge ----------------
// ACT=false (layer 1, feeds W1): fp32 accumulation (error budget tight).
// ACT=true (layer 2, tiny magnitudes): full packed-fp16 accumulation, zero cvt in loop.

template <bool ACT>
__global__ __launch_bounds__(256) void k_agg128h(const _Float16* __restrict__ h, const int* __restrict__ off,
                                                 const ushort_t* __restrict__ ss, const float* __restrict__ dis,
                                                 const float* __restrict__ bias, _Float16* __restrict__ out) {
    int lane = threadIdx.x & 63;
    int sub = lane >> 4;      // 0..3: edge slot
    int li  = lane & 15;      // column group: halfs [li*8, li*8+8)
    int c0  = li * 8;
    int n = blockIdx.x * 4 + (threadIdx.x >> 6);
    int e0 = off[n], e1 = off[n + 1];
    int e = e0;
    float acc[8];
    #pragma unroll
    for (int j = 0; j < 8; ++j) acc[j] = 0.0f;

    if (ACT) {
        half8 hacc = {0, 0, 0, 0, 0, 0, 0, 0};
        for (; e + 8 <= e1; e += 8) {
            int sa = ss[e + sub];
            int sb = ss[e + 4 + sub];
            half8 va = *(const half8*)(h + (size_t)sa * 128 + c0);
            half8 vb = *(const half8*)(h + (size_t)sb * 128 + c0);
            hacc += va + vb;    // packed fp16, no cvt in loop
        }
        #pragma unroll
        for (int j = 0; j < 8; ++j) acc[j] = (float)hacc[j];
    } else {
        for (; e + 8 <= e1; e += 8) {
            int sa = ss[e + sub];
            int sb = ss[e + 4 + sub];
            half8 va = *(const half8*)(h + (size_t)sa * 128 + c0);
            half8 vb = *(const half8*)(h + (size_t)sb * 128 + c0);
            half8 vs = va + vb;
            #pragma unroll
            for (int j = 0; j < 8; ++j) acc[j] += (float)vs[j];
        }
    }
    while (e < e1) {
        int rem = e1 - e;
        int idx = e + sub;
        if (idx >= e1) idx = e1 - 1;
        int s = ss[idx];
        half8 v = *(const half8*)(h + (size_t)s * 128 + c0);
        float w = (sub < rem) ? 1.0f : 0.0f;
        #pragma unroll
        for (int j = 0; j < 8; ++j) acc[j] = fmaf(w, (float)v[j], acc[j]);
        e += 4;
    }

    #pragma unroll
    for (int mask = 32; mask >= 16; mask >>= 1)
        #pragma unroll
        for (int j = 0; j < 8; ++j) acc[j] += __shfl_xor(acc[j], mask, 64);

    float dn = dis[n];
    if (ACT) {
        float m = 0.0f;
        #pragma unroll
        for (int j = 0; j < 8; ++j) {
            float v = fmaxf(fmaf(acc[j], dn, bias[c0 + j]), 0.0f);
            acc[j] = v;
            m = fmaxf(m, v);
        }
        #pragma unroll
        for (int mask = 8; mask > 0; mask >>= 1) m = fmaxf(m, __shfl_xor(m, mask, 64));
        float sum = 0.0f;
        #pragma unroll
        for (int j = 0; j < 8; ++j) {
            float t = __expf(acc[j] - m);
            acc[j] = t;
            sum += t;
        }
        #pragma unroll
        for (int mask = 8; mask > 0; mask >>= 1) sum += __shfl_xor(sum, mask, 64);
        float inv = 1.0f / sum;
        #pragma unroll
        for (int j = 0; j < 8; ++j) acc[j] *= inv;
    } else {
        #pragma unroll
        for (int j = 0; j < 8; ++j) acc[j] *= dn;
    }
    if (sub == 0) {
        half8 o;
        #pragma unroll
        for (int j = 0; j < 8; ++j) o[j] = (_Float16)acc[j];
        *(half8*)(out + (size_t)n * 128 + c0) = o;
    }
}

// ---------------- aggregation, DOUT=64, fp16 rows: eighth-wave (8 lanes x 16B) per edge ----------------
// layer 3: tiny magnitudes -> packed fp16 accumulation.

__global__ __launch_bounds__(256) void k_agg64h(const _Float16* __restrict__ h, const int* __restrict__ off,
                                                const ushort_t* __restrict__ ss, const float* __restrict__ dis,
                                                const float* __restrict__ bias, float* __restrict__ out) {
    int lane = threadIdx.x & 63;
    int sub = lane >> 3;      // 0..7: edge slot
    int li  = lane & 7;       // column group: halfs [li*8, li*8+8)
    int c0  = li * 8;
    int n = blockIdx.x * 4 + (threadIdx.x >> 6);
    int e0 = off[n], e1 = off[n + 1];
    int e = e0;
    float acc[8];
    #pragma unroll
    for (int j = 0; j < 8; ++j) acc[j] = 0.0f;

    half8 hacc = {0, 0, 0, 0, 0, 0, 0, 0};
    for (; e + 8 <= e1; e += 8) {
        int s = ss[e + sub];
        half8 v = *(const half8*)(h + (size_t)s * 64 + c0);
        hacc += v;           // packed fp16
    }
    #pragma unroll
    for (int j = 0; j < 8; ++j) acc[j] = (float)hacc[j];

    int rem = e1 - e;
    if (rem > 0) {
        int idx = e + sub;
        if (idx >= e1) idx = e1 - 1;
        int s = ss[idx];
        half8 v = *(const half8*)(h + (size_t)s * 64 + c0);
        float w = (sub < rem) ? 1.0f : 0.0f;
        #pragma unroll
        for (int j = 0; j < 8; ++j) acc[j] = fmaf(w, (float)v[j], acc[j]);
    }

    #pragma unroll
    for (int mask = 32; mask >= 8; mask >>= 1)
        #pragma unroll
        for (int j = 0; j < 8; ++j) acc[j] += __shfl_xor(acc[j], mask, 64);

    float dn = dis[n];
    float m = 0.0f;
    #pragma unroll
    for (int j = 0; j < 8; ++j) {
        float v = fmaxf(fmaf(acc[j], dn, bias[c0 + j]), 0.0f);
        acc[j] = v;
        m = fmaxf(m, v);
    }
    #pragma unroll
    for (int mask = 4; mask > 0; mask >>= 1) m = fmaxf(m, __shfl_xor(m, mask, 64));
    float sum = 0.0f;
    #pragma unroll
    for (int j = 0; j < 8; ++j) {
        float t = __expf(acc[j] - m);
        acc[j] = t;
        sum += t;
    }
    #pragma unroll
    for (int mask = 4; mask > 0; mask >>= 1) sum += __shfl_xor(sum, mask, 64);
    float inv = 1.0f / sum;
    if (sub == 0) {
        float* op = out + (size_t)n * 64 + c0;
        *(float4*)(op)     = make_float4(acc[0] * inv, acc[1] * inv, acc[2] * inv, acc[3] * inv);
        *(float4*)(op + 4) = make_float4(acc[4] * inv, acc[5] * inv, acc[6] * inv, acc[7] * inv);
    }
}

// ---------------- launch ----------------

extern "C" void kernel_launch(void* const* d_in, const int* in_sizes, int n_in,
                              void* d_out, int out_size, void* d_ws, size_t ws_size,
                              hipStream_t stream) {
    const float* x  = (const float*)d_in[0];
    const int*   ei = (const int*)d_in[1];
    const float* W1 = (const float*)d_in[2];
    const float* b1 = (const float*)d_in[3];
    const float* W2 = (const float*)d_in[4];
    const float* b2 = (const float*)d_in[5];
    const float* W3 = (const float*)d_in[6];
    const float* b3 = (const float*)d_in[7];
    const int* srcE = ei;
    const int* dstE = ei + N_EDGES;

    char* p = (char*)d_ws;
    auto carve = [&](size_t bytes) {
        char* q = p;
        p += (bytes + 255) & ~(size_t)255;
        return q;
    };
    int*          deg   = (int*)carve(sizeof(int) * N_NODES);
    int*          off   = (int*)carve(sizeof(int) * (N_NODES + 1));
    float*        dis   = (float*)carve(sizeof(float) * N_NODES);
    int*          bsum  = (int*)carve(sizeof(int) * 256);
    u64*          ed2   = (u64*)carve(sizeof(u64) * N_EDGES);
    ushort_t*     ssort = (ushort_t*)carve(sizeof(ushort_t) * E_TOT);
    short*        w1h   = (short*)carve(sizeof(short) * 128 * 256);
    short*        w1l   = (short*)carve(sizeof(short) * 128 * 256);
    short*        w2h   = (short*)carve(sizeof(short) * 256 * 128);
    short*        w2l   = (short*)carve(sizeof(short) * 256 * 128);
    short*        w3h   = (short*)carve(sizeof(short) * 128 * 64);
    short*        w3l   = (short*)carve(sizeof(short) * 128 * 64);
    _Float16*     xh    = (_Float16*)carve(sizeof(_Float16) * (size_t)N_NODES * 128);
    _Float16*     a0h   = (_Float16*)carve(sizeof(_Float16) * (size_t)N_NODES * 128);
    _Float16*     x1h   = (_Float16*)carve(sizeof(_Float16) * (size_t)N_NODES * 256);
    _Float16*     x2h   = (_Float16*)carve(sizeof(_Float16) * (size_t)N_NODES * 128);
    _Float16*     hh    = (_Float16*)carve(sizeof(_Float16) * (size_t)N_NODES * 128);  // h2' then h3'

    (void)hipMemsetAsync(deg, 0, sizeof(int) * N_NODES, stream);
    k_hist<<<(N_EDGES + 1023) / 1024, 256, 0, stream>>>(srcE, dstE, deg, ed2);
    k_scan1<<<N_NODES / 256, 256, 0, stream>>>(deg, off, bsum);
    k_scan2<<<1, 256, 0, stream>>>(bsum);
    k_scan3<<<N_NODES / 256, 256, 0, stream>>>(deg, off, dis, bsum, ssort);
    k_scatter<<<(N_EDGES + 255) / 256, 256, 0, stream>>>(ed2, off, ssort);
    k_convx<<<(N_NODES * 128 / 4) / 256, 256, 0, stream>>>(x, dis, xh);
    k_convw3<<<(G1 + G2 + G3 + 255) / 256, 256, 0, stream>>>(W1, w1h, w1l, W2, w2h, w2l, W3, w3h, w3l);

    // layer 1 (agg-first): a0[n] = dis[n] * sum xh[src]  (xh pre-scaled by dis[src]), fp16
    k_agg128h<false><<<N_NODES / 4, 256, 0, stream>>>(xh, off, ssort, dis, nullptr, a0h);
    // x1 = softmax(relu(a0@W1 + b1)), fp16
    k_mm<128, 256, true><<<N_NODES / 64, 256, 0, stream>>>(a0h, w1h, w1l, b1, nullptr, x1h);
    // layer 2: h2' = fp16(dis .* (x1@W2)); x2 = softmax(relu(dis[n]*segsum(h2') + b2)), fp16
    k_mm<256, 128, false><<<N_NODES / 64, 256, 0, stream>>>(x1h, w2h, w2l, nullptr, dis, hh);
    k_agg128h<true><<<N_NODES / 4, 256, 0, stream>>>(hh, off, ssort, dis, b2, x2h);
    // layer 3: h3' = fp16(dis .* (x2@W3)); out = softmax(relu(dis[n]*segsum(h3') + b3)), fp32
    k_mm<128, 64, false><<<N_NODES / 64, 256, 0, stream>>>(x2h, w3h, w3l, nullptr, dis, hh);
    k_agg64h<<<N_NODES / 4, 256, 0, stream>>>(hh, off, ssort, dis, b3, (float*)d_out);
}

// Round 15
// 352.330 us; speedup vs baseline: 1.0398x; 1.0398x over previous
//
#include <hip/hip_runtime.h>
#include <cstdint>
#include <cstddef>

#define N_NODES 65536
#define N_EDGES 1048576
#define E_TOT   (N_EDGES + N_NODES)

using short8  = __attribute__((ext_vector_type(8))) short;
using floatx4 = __attribute__((ext_vector_type(4))) float;
using half8   = __attribute__((ext_vector_type(8))) _Float16;
using half4   = __attribute__((ext_vector_type(4))) _Float16;
typedef unsigned short ushort_t;
typedef unsigned long long u64;

// split fp32 -> bf16 hi (RTN) + bf16 lo (trunc of residual)
__device__ inline void split_bf16(float a, short& hi, short& lo) {
    unsigned u  = __float_as_uint(a);
    unsigned hr = (u + 0x7fffu + ((u >> 16) & 1u)) >> 16;
    float    hf = __uint_as_float(hr << 16);
    hi = (short)hr;
    float    lf = a - hf;
    lo = (short)(__float_as_uint(lf) >> 16);
}

// ---------------- preprocessing ----------------
// deg[] zeroed via hipMemsetAsync. Self-loop handled outside the edge stream.

// histogram + deterministic rank capture: ed2[e] = rank<<32 | (s<<16) | d
__global__ void k_hist(const int* __restrict__ src, const int* __restrict__ dst,
                       int* __restrict__ deg, u64* __restrict__ ed2) {
    int base = blockIdx.x * 1024;
    #pragma unroll
    for (int j = 0; j < 4; ++j) {
        int e = base + j * 256 + threadIdx.x;
        if (e < N_EDGES) {
            int d = __builtin_nontemporal_load(&dst[e]);
            int s = __builtin_nontemporal_load(&src[e]);
            int rank = atomicAdd(&deg[d], 1);
            u64 rec = ((u64)(unsigned)rank << 32) | (u64)((unsigned)d | ((unsigned)s << 16));
            __builtin_nontemporal_store(rec, &ed2[e]);
        }
    }
}

// block-local exclusive scan + block sums + dis
__global__ __launch_bounds__(256) void k_scan1(const int* __restrict__ deg, int* __restrict__ off,
                                               int* __restrict__ bsum, float* __restrict__ dis) {
    __shared__ int sb[256];
    int tid = threadIdx.x;
    int g = blockIdx.x * 256 + tid;
    int v = deg[g] + 1;               // +1: self loop
    dis[g] = rsqrtf((float)v);
    sb[tid] = v;
    __syncthreads();
    #pragma unroll
    for (int s = 1; s < 256; s <<= 1) {
        int t = (tid >= s) ? sb[tid - s] : 0;
        __syncthreads();
        sb[tid] += t;
        __syncthreads();
    }
    off[g] = sb[tid] - v;
    if (tid == 255) bsum[blockIdx.x] = sb[255];
}

// finalize offsets (re-scanning bsum locally -- replaces the old scan2 launch),
// and place the self-loop edge at the end of each segment
__global__ __launch_bounds__(256) void k_scan3(const int* __restrict__ deg, int* __restrict__ off,
                                               const int* __restrict__ bsum, ushort_t* __restrict__ ssort) {
    __shared__ int sb[256];
    int tid = threadIdx.x;
    int v = bsum[tid];
    sb[tid] = v;
    __syncthreads();
    #pragma unroll
    for (int s = 1; s < 256; s <<= 1) {
        int t = (tid >= s) ? sb[tid - s] : 0;
        __syncthreads();
        sb[tid] += t;
        __syncthreads();
    }
    int base = (blockIdx.x == 0) ? 0 : sb[blockIdx.x - 1];
    int g = blockIdx.x * 256 + tid;
    int d = deg[g];
    int o = off[g] + base;
    off[g] = o;
    ssort[o + d] = (ushort_t)g;             // self loop at segment end
    if (g == 0) off[N_NODES] = E_TOT;
}

// ---------------- fused: scatter + convx + convw3 (independent work, one launch) ----------------

#define G1 (16 * 4 * 64)   // W1 128x256
#define G2 (8 * 8 * 64)    // W2 256x128
#define G3 (4 * 4 * 64)    // W3 128x64
#define NBX 8192           // convx blocks
#define NBS 4096           // scatter blocks
#define NBW ((G1 + G2 + G3 + 255) / 256)

__device__ inline void convw_one(const float* W, int K, int N, short* Bh, short* Bl, int g) {
    int lane = g & 63;
    int kt = (g >> 6) % (K / 32);
    int nt = (g >> 6) / (K / 32);
    int n = nt * 16 + (lane & 15);
    int kbase = kt * 32 + (lane >> 4) * 8;
    #pragma unroll
    for (int j = 0; j < 8; ++j) {
        short h, l;
        split_bf16(W[(size_t)(kbase + j) * N + n], h, l);
        Bh[(size_t)g * 8 + j] = h;
        Bl[(size_t)g * 8 + j] = l;
    }
}

__global__ __launch_bounds__(256) void k_fused(
        const float* __restrict__ x, const float* __restrict__ dis, _Float16* __restrict__ xh,
        const u64* __restrict__ ed2, const int* __restrict__ off, ushort_t* __restrict__ ssort,
        const float* __restrict__ W1, short* __restrict__ w1h, short* __restrict__ w1l,
        const float* __restrict__ W2, short* __restrict__ w2h, short* __restrict__ w2l,
        const float* __restrict__ W3, short* __restrict__ w3h, short* __restrict__ w3l) {
    int b = blockIdx.x;
    if (b < NBX) {
        // convx: xh = fp16(dis[row] * x), 4 floats per thread
        int idx = (b * 256 + threadIdx.x) * 4;
        int row = idx >> 7;
        float d = dis[row];
        float4 v = *(const float4*)(x + idx);
        half4 o = {(_Float16)(d * v.x), (_Float16)(d * v.y), (_Float16)(d * v.z), (_Float16)(d * v.w)};
        *(half4*)(xh + idx) = o;
    } else if (b < NBX + NBS) {
        // atomic-free scatter: slot = off[d] + rank
        int e = (b - NBX) * 256 + threadIdx.x;
        if (e < N_EDGES) {
            u64 v = __builtin_nontemporal_load(&ed2[e]);
            int d = (int)(v & 0xffffu);
            int s = (int)((v >> 16) & 0xffffu);
            int rank = (int)(v >> 32);
            ssort[off[d] + rank] = (ushort_t)s;
        }
    } else {
        int g = (b - NBX - NBS) * 256 + threadIdx.x;
        if (g < G1)                 convw_one(W1, 128, 256, w1h, w1l, g);
        else if (g < G1 + G2)       convw_one(W2, 256, 128, w2h, w2l, g - G1);
        else if (g < G1 + G2 + G3)  convw_one(W3, 128, 64, w3h, w3l, g - G1 - G2);
    }
}

// ---------------- split-bf16 MFMA GEMM: C[M,N] = A[M,K] @ W ----------------
// A is fp16 rows. ACT: C = softmax(relu(C + bias)) -> fp16.
// else: C = dis[row] * C -> fp16 (feeds the gather).

template <int K, int N, bool ACT>
__global__ __launch_bounds__(256) void k_mm(const _Float16* __restrict__ A,
                                            const short* __restrict__ Bh, const short* __restrict__ Bl,
                                            const float* __restrict__ bias, const float* __restrict__ dis,
                                            _Float16* __restrict__ Cout) {
    constexpr int NT = N / 16;
    constexpr int KT = K / 32;
    __shared__ short Ah[4 * 64 * 8];
    __shared__ short Al[4 * 64 * 8];
    int tid = threadIdx.x;
    int wave = tid >> 6, lane = tid & 63;
    int quad = lane >> 4, col = lane & 15;
    size_t row0 = (size_t)blockIdx.x * 64;

    floatx4 acc[NT];
    #pragma unroll
    for (int t = 0; t < NT; ++t) acc[t] = (floatx4)0.0f;

    int srow = tid >> 2;
    int sdst = ((srow >> 4) * 64 + (srow & 15) + ((tid & 3) << 4)) * 8;
    const _Float16* arow = A + (row0 + srow) * K + (tid & 3) * 8;

    for (int kt = 0; kt < KT; ++kt) {
        half8 a8 = *(const half8*)(arow + kt * 32);
        short h[8], l[8];
        #pragma unroll
        for (int j = 0; j < 8; ++j) split_bf16((float)a8[j], h[j], l[j]);
        __syncthreads();
        *(short8*)(&Ah[sdst]) = *(short8*)h;
        *(short8*)(&Al[sdst]) = *(short8*)l;
        __syncthreads();
        short8 afh = *(short8*)(&Ah[(wave * 64 + lane) * 8]);
        short8 afl = *(short8*)(&Al[(wave * 64 + lane) * 8]);
        #pragma unroll
        for (int nt = 0; nt < NT; ++nt) {
            size_t bi = ((size_t)(nt * KT + kt) * 64 + lane);
            short8 bfh = ((const short8*)Bh)[bi];
            short8 bfl = ((const short8*)Bl)[bi];
            acc[nt] = __builtin_amdgcn_mfma_f32_16x16x32_bf16(afh, bfh, acc[nt], 0, 0, 0);
            acc[nt] = __builtin_amdgcn_mfma_f32_16x16x32_bf16(afh, bfl, acc[nt], 0, 0, 0);
            acc[nt] = __builtin_amdgcn_mfma_f32_16x16x32_bf16(afl, bfh, acc[nt], 0, 0, 0);
        }
    }

    size_t rbase = row0 + wave * 16 + quad * 4;
    if (!ACT) {
        float4 d4 = *(const float4*)(dis + rbase);
        float dr[4] = {d4.x, d4.y, d4.z, d4.w};
        #pragma unroll
        for (int nt = 0; nt < NT; ++nt)
            #pragma unroll
            for (int r = 0; r < 4; ++r)
                Cout[(rbase + r) * N + nt * 16 + col] = (_Float16)(acc[nt][r] * dr[r]);
    } else {
        float bv[NT];
        #pragma unroll
        for (int nt = 0; nt < NT; ++nt) bv[nt] = bias[nt * 16 + col];
        float mr[4] = {0.f, 0.f, 0.f, 0.f};
        #pragma unroll
        for (int nt = 0; nt < NT; ++nt)
            #pragma unroll
            for (int r = 0; r < 4; ++r) {
                float v = fmaxf(acc[nt][r] + bv[nt], 0.0f);
                acc[nt][r] = v;
                mr[r] = fmaxf(mr[r], v);
            }
        #pragma unroll
        for (int mask = 1; mask < 16; mask <<= 1)
            #pragma unroll
            for (int r = 0; r < 4; ++r) mr[r] = fmaxf(mr[r], __shfl_xor(mr[r], mask, 64));
        float sr[4] = {0.f, 0.f, 0.f, 0.f};
        #pragma unroll
        for (int nt = 0; nt < NT; ++nt)
            #pragma unroll
            for (int r = 0; r < 4; ++r) {
                float t = __expf(acc[nt][r] - mr[r]);
                acc[nt][r] = t;
                sr[r] += t;
            }
        #pragma unroll
        for (int mask = 1; mask < 16; mask <<= 1)
            #pragma unroll
            for (int r = 0; r < 4; ++r) sr[r] += __shfl_xor(sr[r], mask, 64);
        float inv[4];
        #pragma unroll
        for (int r = 0; r < 4; ++r) inv[r] = 1.0f / sr[r];
        #pragma unroll
        for (int nt = 0; nt < NT; ++nt)
            #pragma unroll
            for (int r = 0; r < 4; ++r)
                Cout[(rbase + r) * N + nt * 16 + col] = (_Float16)(acc[nt][r] * inv[r]);
    }
}

// ---------------- aggregation, DOUT=128, fp16 rows: quarter-wave (16 lanes x 16B) per edge ----------------
// 16-edge main loop (4 gathers in flight per lane) -> 8 -> masked-4 remainder.

template <bool ACT>
__global__ __launch_bounds__(256) void k_agg128h(const _Float16* __restrict__ h, const int* __restrict__ off,
                                                 const ushort_t* __restrict__ ss, const float* __restrict__ dis,
                                                 const float* __restrict__ bias, _Float16* __restrict__ out) {
    int lane = threadIdx.x & 63;
    int sub = lane >> 4;      // 0..3: edge slot
    int li  = lane & 15;      // column group: halfs [li*8, li*8+8)
    int c0  = li * 8;
    int n = blockIdx.x * 4 + (threadIdx.x >> 6);
    int e0 = off[n], e1 = off[n + 1];
    int e = e0;
    float acc[8];
    #pragma unroll
    for (int j = 0; j < 8; ++j) acc[j] = 0.0f;

    if (ACT) {
        half8 hacc = {0, 0, 0, 0, 0, 0, 0, 0};
        for (; e + 16 <= e1; e += 16) {
            int s0 = ss[e + sub];
            int s1 = ss[e + 4 + sub];
            int s2 = ss[e + 8 + sub];
            int s3 = ss[e + 12 + sub];
            half8 v0 = *(const half8*)(h + (size_t)s0 * 128 + c0);
            half8 v1 = *(const half8*)(h + (size_t)s1 * 128 + c0);
            half8 v2 = *(const half8*)(h + (size_t)s2 * 128 + c0);
            half8 v3 = *(const half8*)(h + (size_t)s3 * 128 + c0);
            hacc += (v0 + v1) + (v2 + v3);
        }
        for (; e + 8 <= e1; e += 8) {
            int sa = ss[e + sub];
            int sb = ss[e + 4 + sub];
            half8 va = *(const half8*)(h + (size_t)sa * 128 + c0);
            half8 vb = *(const half8*)(h + (size_t)sb * 128 + c0);
            hacc += va + vb;
        }
        #pragma unroll
        for (int j = 0; j < 8; ++j) acc[j] = (float)hacc[j];
    } else {
        for (; e + 16 <= e1; e += 16) {
            int s0 = ss[e + sub];
            int s1 = ss[e + 4 + sub];
            int s2 = ss[e + 8 + sub];
            int s3 = ss[e + 12 + sub];
            half8 v0 = *(const half8*)(h + (size_t)s0 * 128 + c0);
            half8 v1 = *(const half8*)(h + (size_t)s1 * 128 + c0);
            half8 v2 = *(const half8*)(h + (size_t)s2 * 128 + c0);
            half8 v3 = *(const half8*)(h + (size_t)s3 * 128 + c0);
            half8 vs = (v0 + v1) + (v2 + v3);
            #pragma unroll
            for (int j = 0; j < 8; ++j) acc[j] += (float)vs[j];
        }
        for (; e + 8 <= e1; e += 8) {
            int sa = ss[e + sub];
            int sb = ss[e + 4 + sub];
            half8 va = *(const half8*)(h + (size_t)sa * 128 + c0);
            half8 vb = *(const half8*)(h + (size_t)sb * 128 + c0);
            half8 vs = va + vb;
            #pragma unroll
            for (int j = 0; j < 8; ++j) acc[j] += (float)vs[j];
        }
    }
    while (e < e1) {
        int rem = e1 - e;
        int idx = e + sub;
        if (idx >= e1) idx = e1 - 1;
        int s = ss[idx];
        half8 v = *(const half8*)(h + (size_t)s * 128 + c0);
        float w = (sub < rem) ? 1.0f : 0.0f;
        #pragma unroll
        for (int j = 0; j < 8; ++j) acc[j] = fmaf(w, (float)v[j], acc[j]);
        e += 4;
    }

    #pragma unroll
    for (int mask = 32; mask >= 16; mask >>= 1)
        #pragma unroll
        for (int j = 0; j < 8; ++j) acc[j] += __shfl_xor(acc[j], mask, 64);

    float dn = dis[n];
    if (ACT) {
        float m = 0.0f;
        #pragma unroll
        for (int j = 0; j < 8; ++j) {
            float v = fmaxf(fmaf(acc[j], dn, bias[c0 + j]), 0.0f);
            acc[j] = v;
            m = fmaxf(m, v);
        }
        #pragma unroll
        for (int mask = 8; mask > 0; mask >>= 1) m = fmaxf(m, __shfl_xor(m, mask, 64));
        float sum = 0.0f;
        #pragma unroll
        for (int j = 0; j < 8; ++j) {
            float t = __expf(acc[j] - m);
            acc[j] = t;
            sum += t;
        }
        #pragma unroll
        for (int mask = 8; mask > 0; mask >>= 1) sum += __shfl_xor(sum, mask, 64);
        float inv = 1.0f / sum;
        #pragma unroll
        for (int j = 0; j < 8; ++j) acc[j] *= inv;
    } else {
        #pragma unroll
        for (int j = 0; j < 8; ++j) acc[j] *= dn;
    }
    if (sub == 0) {
        half8 o;
        #pragma unroll
        for (int j = 0; j < 8; ++j) o[j] = (_Float16)acc[j];
        *(half8*)(out + (size_t)n * 128 + c0) = o;
    }
}

// ---------------- aggregation, DOUT=64, fp16 rows: eighth-wave (8 lanes x 16B) per edge ----------------

__global__ __launch_bounds__(256) void k_agg64h(const _Float16* __restrict__ h, const int* __restrict__ off,
                                                const ushort_t* __restrict__ ss, const float* __restrict__ dis,
                                                const float* __restrict__ bias, float* __restrict__ out) {
    int lane = threadIdx.x & 63;
    int sub = lane >> 3;      // 0..7: edge slot
    int li  = lane & 7;       // column group: halfs [li*8, li*8+8)
    int c0  = li * 8;
    int n = blockIdx.x * 4 + (threadIdx.x >> 6);
    int e0 = off[n], e1 = off[n + 1];
    int e = e0;
    float acc[8];
    #pragma unroll
    for (int j = 0; j < 8; ++j) acc[j] = 0.0f;

    half8 hacc = {0, 0, 0, 0, 0, 0, 0, 0};
    for (; e + 16 <= e1; e += 16) {
        int s0 = ss[e + sub];
        int s1 = ss[e + 8 + sub];
        half8 v0 = *(const half8*)(h + (size_t)s0 * 64 + c0);
        half8 v1 = *(const half8*)(h + (size_t)s1 * 64 + c0);
        hacc += v0 + v1;
    }
    for (; e + 8 <= e1; e += 8) {
        int s = ss[e + sub];
        half8 v = *(const half8*)(h + (size_t)s * 64 + c0);
        hacc += v;
    }
    #pragma unroll
    for (int j = 0; j < 8; ++j) acc[j] = (float)hacc[j];

    int rem = e1 - e;
    if (rem > 0) {
        int idx = e + sub;
        if (idx >= e1) idx = e1 - 1;
        int s = ss[idx];
        half8 v = *(const half8*)(h + (size_t)s * 64 + c0);
        float w = (sub < rem) ? 1.0f : 0.0f;
        #pragma unroll
        for (int j = 0; j < 8; ++j) acc[j] = fmaf(w, (float)v[j], acc[j]);
    }

    #pragma unroll
    for (int mask = 32; mask >= 8; mask >>= 1)
        #pragma unroll
        for (int j = 0; j < 8; ++j) acc[j] += __shfl_xor(acc[j], mask, 64);

    float dn = dis[n];
    float m = 0.0f;
    #pragma unroll
    for (int j = 0; j < 8; ++j) {
        float v = fmaxf(fmaf(acc[j], dn, bias[c0 + j]), 0.0f);
        acc[j] = v;
        m = fmaxf(m, v);
    }
    #pragma unroll
    for (int mask = 4; mask > 0; mask >>= 1) m = fmaxf(m, __shfl_xor(m, mask, 64));
    float sum = 0.0f;
    #pragma unroll
    for (int j = 0; j < 8; ++j) {
        float t = __expf(acc[j] - m);
        acc[j] = t;
        sum += t;
    }
    #pragma unroll
    for (int mask = 4; mask > 0; mask >>= 1) sum += __shfl_xor(sum, mask, 64);
    float inv = 1.0f / sum;
    if (sub == 0) {
        float* op = out + (size_t)n * 64 + c0;
        *(float4*)(op)     = make_float4(acc[0] * inv, acc[1] * inv, acc[2] * inv, acc[3] * inv);
        *(float4*)(op + 4) = make_float4(acc[4] * inv, acc[5] * inv, acc[6] * inv, acc[7] * inv);
    }
}

// ---------------- launch ----------------

extern "C" void kernel_launch(void* const* d_in, const int* in_sizes, int n_in,
                              void* d_out, int out_size, void* d_ws, size_t ws_size,
                              hipStream_t stream) {
    const float* x  = (const float*)d_in[0];
    const int*   ei = (const int*)d_in[1];
    const float* W1 = (const float*)d_in[2];
    const float* b1 = (const float*)d_in[3];
    const float* W2 = (const float*)d_in[4];
    const float* b2 = (const float*)d_in[5];
    const float* W3 = (const float*)d_in[6];
    const float* b3 = (const float*)d_in[7];
    const int* srcE = ei;
    const int* dstE = ei + N_EDGES;

    char* p = (char*)d_ws;
    auto carve = [&](size_t bytes) {
        char* q = p;
        p += (bytes + 255) & ~(size_t)255;
        return q;
    };
    int*          deg   = (int*)carve(sizeof(int) * N_NODES);
    int*          off   = (int*)carve(sizeof(int) * (N_NODES + 1));
    float*        dis   = (float*)carve(sizeof(float) * N_NODES);
    int*          bsum  = (int*)carve(sizeof(int) * 256);
    u64*          ed2   = (u64*)carve(sizeof(u64) * N_EDGES);
    ushort_t*     ssort = (ushort_t*)carve(sizeof(ushort_t) * E_TOT);
    short*        w1h   = (short*)carve(sizeof(short) * 128 * 256);
    short*        w1l   = (short*)carve(sizeof(short) * 128 * 256);
    short*        w2h   = (short*)carve(sizeof(short) * 256 * 128);
    short*        w2l   = (short*)carve(sizeof(short) * 256 * 128);
    short*        w3h   = (short*)carve(sizeof(short) * 128 * 64);
    short*        w3l   = (short*)carve(sizeof(short) * 128 * 64);
    _Float16*     xh    = (_Float16*)carve(sizeof(_Float16) * (size_t)N_NODES * 128);
    _Float16*     a0h   = (_Float16*)carve(sizeof(_Float16) * (size_t)N_NODES * 128);
    _Float16*     x1h   = (_Float16*)carve(sizeof(_Float16) * (size_t)N_NODES * 256);
    _Float16*     x2h   = (_Float16*)carve(sizeof(_Float16) * (size_t)N_NODES * 128);
    _Float16*     hh    = (_Float16*)carve(sizeof(_Float16) * (size_t)N_NODES * 128);  // h2' then h3'

    (void)hipMemsetAsync(deg, 0, sizeof(int) * N_NODES, stream);
    k_hist<<<(N_EDGES + 1023) / 1024, 256, 0, stream>>>(srcE, dstE, deg, ed2);
    k_scan1<<<N_NODES / 256, 256, 0, stream>>>(deg, off, bsum, dis);
    k_scan3<<<N_NODES / 256, 256, 0, stream>>>(deg, off, bsum, ssort);
    k_fused<<<NBX + NBS + NBW, 256, 0, stream>>>(x, dis, xh, ed2, off, ssort,
                                                 W1, w1h, w1l, W2, w2h, w2l, W3, w3h, w3l);

    // layer 1 (agg-first): a0[n] = dis[n] * sum xh[src]  (xh pre-scaled by dis[src]), fp16
    k_agg128h<false><<<N_NODES / 4, 256, 0, stream>>>(xh, off, ssort, dis, nullptr, a0h);
    // x1 = softmax(relu(a0@W1 + b1)), fp16
    k_mm<128, 256, true><<<N_NODES / 64, 256, 0, stream>>>(a0h, w1h, w1l, b1, nullptr, x1h);
    // layer 2: h2' = fp16(dis .* (x1@W2)); x2 = softmax(relu(dis[n]*segsum(h2') + b2)), fp16
    k_mm<256, 128, false><<<N_NODES / 64, 256, 0, stream>>>(x1h, w2h, w2l, nullptr, dis, hh);
    k_agg128h<true><<<N_NODES / 4, 256, 0, stream>>>(hh, off, ssort, dis, b2, x2h);
    // layer 3: h3' = fp16(dis .* (x2@W3)); out = softmax(relu(dis[n]*segsum(h3') + b3)), fp32
    k_mm<128, 64, false><<<N_NODES / 64, 256, 0, stream>>>(x2h, w3h, w3l, nullptr, dis, hh);
    k_agg64h<<<N_NODES / 4, 256, 0, stream>>>(hh, off, ssort, dis, b3, (float*)d_out);
}

// Round 16
// 319.584 us; speedup vs baseline: 1.1464x; 1.1025x over previous
//
#include <hip/hip_runtime.h>
#include <cstdint>
#include <cstddef>

#define N_NODES 65536
#define N_EDGES 1048576
#define E_TOT   (N_EDGES + N_NODES)
#define CAP     5120   // bucket region capacity (mean 4096, +16 sigma)

using short8  = __attribute__((ext_vector_type(8))) short;
using floatx4 = __attribute__((ext_vector_type(4))) float;
using half8   = __attribute__((ext_vector_type(8))) _Float16;
using half4   = __attribute__((ext_vector_type(4))) _Float16;
typedef unsigned short ushort_t;

// split fp32 -> bf16 hi (RTN) + bf16 lo (trunc of residual)
__device__ inline void split_bf16(float a, short& hi, short& lo) {
    unsigned u  = __float_as_uint(a);
    unsigned hr = (u + 0x7fffu + ((u >> 16) & 1u)) >> 16;
    float    hf = __uint_as_float(hr << 16);
    hi = (short)hr;
    float    lf = a - hf;
    lo = (short)(__float_as_uint(lf) >> 16);
}

// ---------------- preprocessing: bucket counting sort (no 1M returning global atomics) ----------------
// gcur[256] zeroed via hipMemsetAsync each call.

// pass 1: bucket edges by dst>>8 into fixed-capacity regions. LDS histogram + 256
// returning global atomics per block (65536 total); per-edge ranks via LDS atomics.
__global__ __launch_bounds__(1024) void k_bucket(const int* __restrict__ src, const int* __restrict__ dst,
                                                 int* __restrict__ gcur, unsigned* __restrict__ pk) {
    __shared__ int cnt[256];
    __shared__ int cur[256];
    int tid = threadIdx.x;
    if (tid < 256) cnt[tid] = 0;
    __syncthreads();
    int base = blockIdx.x * 4096;
    #pragma unroll
    for (int j = 0; j < 4; ++j) {
        int d = __builtin_nontemporal_load(&dst[base + j * 1024 + tid]);
        atomicAdd(&cnt[d >> 8], 1);
    }
    __syncthreads();
    if (tid < 256) cur[tid] = CAP * tid + atomicAdd(&gcur[tid], cnt[tid]);
    __syncthreads();
    #pragma unroll
    for (int j = 0; j < 4; ++j) {
        int e = base + j * 1024 + tid;
        int d = __builtin_nontemporal_load(&dst[e]);
        int s = __builtin_nontemporal_load(&src[e]);
        int pos = atomicAdd(&cur[d >> 8], 1);
        pk[pos] = ((unsigned)s << 16) | (unsigned)d;
    }
}

// pass 2 (1 block): exclusive scan of bucket sizes (+256 self loops each) -> region offsets
__global__ __launch_bounds__(256) void k_boff(const int* __restrict__ gcur, int* __restrict__ boff,
                                              int* __restrict__ off) {
    __shared__ int sb[256];
    int tid = threadIdx.x;
    int v = gcur[tid] + 256;     // edges + one self loop per dst
    sb[tid] = v;
    __syncthreads();
    #pragma unroll
    for (int s = 1; s < 256; s <<= 1) {
        int t = (tid >= s) ? sb[tid - s] : 0;
        __syncthreads();
        sb[tid] += t;
        __syncthreads();
    }
    boff[tid] = sb[tid] - v;
    if (tid == 255) boff[256] = sb[255];
    if (tid == 0) off[N_NODES] = E_TOT;
}

// pass 3: per-bucket LDS counting sort by dst&255 -> off, dis, self loops, sorted ssort.
// All rank atomics are LDS-local.
__global__ __launch_bounds__(1024) void k_sortb(const unsigned* __restrict__ pk, const int* __restrict__ gcur,
                                                const int* __restrict__ boff, int* __restrict__ off,
                                                float* __restrict__ dis, ushort_t* __restrict__ ssort) {
    __shared__ int cnt[256];
    __shared__ int sb[256];
    __shared__ int cur[256];
    int b = blockIdx.x;
    int tid = threadIdx.x;
    int n = gcur[b];
    const unsigned* p = pk + (size_t)b * CAP;
    if (tid < 256) cnt[tid] = 0;
    __syncthreads();
    for (int i = tid; i < n; i += 1024) atomicAdd(&cnt[p[i] & 255u], 1);
    __syncthreads();
    if (tid < 256) sb[tid] = cnt[tid];
    __syncthreads();
    #pragma unroll
    for (int s = 1; s < 256; s <<= 1) {
        int t = (tid < 256 && tid >= s) ? sb[tid - s] : 0;
        __syncthreads();
        if (tid < 256) sb[tid] += t;
        __syncthreads();
    }
    if (tid < 256) {
        int deg = cnt[tid];
        int o = boff[b] + (sb[tid] - deg) + tid;   // +tid: one self-loop slot per preceding dst
        int d = b * 256 + tid;
        off[d] = o;
        dis[d] = rsqrtf((float)(deg + 1));
        ssort[o + deg] = (ushort_t)d;              // self loop at segment end
        cur[tid] = o;
    }
    __syncthreads();
    for (int i = tid; i < n; i += 1024) {
        unsigned v = p[i];
        int pos = atomicAdd(&cur[v & 255u], 1);
        ssort[pos] = (ushort_t)(v >> 16);
    }
}

// ---------------- fused: convx + convw3 ----------------

#define G1 (16 * 4 * 64)   // W1 128x256
#define G2 (8 * 8 * 64)    // W2 256x128
#define G3 (4 * 4 * 64)    // W3 128x64
#define NBX 8192           // convx blocks
#define NBW ((G1 + G2 + G3 + 255) / 256)

__device__ inline void convw_one(const float* W, int K, int N, short* Bh, short* Bl, int g) {
    int lane = g & 63;
    int kt = (g >> 6) % (K / 32);
    int nt = (g >> 6) / (K / 32);
    int n = nt * 16 + (lane & 15);
    int kbase = kt * 32 + (lane >> 4) * 8;
    #pragma unroll
    for (int j = 0; j < 8; ++j) {
        short h, l;
        split_bf16(W[(size_t)(kbase + j) * N + n], h, l);
        Bh[(size_t)g * 8 + j] = h;
        Bl[(size_t)g * 8 + j] = l;
    }
}

__global__ __launch_bounds__(256) void k_fused(
        const float* __restrict__ x, const float* __restrict__ dis, _Float16* __restrict__ xh,
        const float* __restrict__ W1, short* __restrict__ w1h, short* __restrict__ w1l,
        const float* __restrict__ W2, short* __restrict__ w2h, short* __restrict__ w2l,
        const float* __restrict__ W3, short* __restrict__ w3h, short* __restrict__ w3l) {
    int b = blockIdx.x;
    if (b < NBX) {
        int idx = (b * 256 + threadIdx.x) * 4;
        int row = idx >> 7;
        float d = dis[row];
        float4 v = *(const float4*)(x + idx);
        half4 o = {(_Float16)(d * v.x), (_Float16)(d * v.y), (_Float16)(d * v.z), (_Float16)(d * v.w)};
        *(half4*)(xh + idx) = o;
    } else {
        int g = (b - NBX) * 256 + threadIdx.x;
        if (g < G1)                 convw_one(W1, 128, 256, w1h, w1l, g);
        else if (g < G1 + G2)       convw_one(W2, 256, 128, w2h, w2l, g - G1);
        else if (g < G1 + G2 + G3)  convw_one(W3, 128, 64, w3h, w3l, g - G1 - G2);
    }
}

// ---------------- split-bf16 MFMA GEMM: C[M,N] = A[M,K] @ W ----------------
// A is fp16 rows. ACT: C = softmax(relu(C + bias)) -> fp16.
// else: C = dis[row] * C -> fp16 (feeds the gather).

template <int K, int N, bool ACT>
__global__ __launch_bounds__(256) void k_mm(const _Float16* __restrict__ A,
                                            const short* __restrict__ Bh, const short* __restrict__ Bl,
                                            const float* __restrict__ bias, const float* __restrict__ dis,
                                            _Float16* __restrict__ Cout) {
    constexpr int NT = N / 16;
    constexpr int KT = K / 32;
    __shared__ short Ah[4 * 64 * 8];
    __shared__ short Al[4 * 64 * 8];
    int tid = threadIdx.x;
    int wave = tid >> 6, lane = tid & 63;
    int quad = lane >> 4, col = lane & 15;
    size_t row0 = (size_t)blockIdx.x * 64;

    floatx4 acc[NT];
    #pragma unroll
    for (int t = 0; t < NT; ++t) acc[t] = (floatx4)0.0f;

    int srow = tid >> 2;
    int sdst = ((srow >> 4) * 64 + (srow & 15) + ((tid & 3) << 4)) * 8;
    const _Float16* arow = A + (row0 + srow) * K + (tid & 3) * 8;

    for (int kt = 0; kt < KT; ++kt) {
        half8 a8 = *(const half8*)(arow + kt * 32);
        short h[8], l[8];
        #pragma unroll
        for (int j = 0; j < 8; ++j) split_bf16((float)a8[j], h[j], l[j]);
        __syncthreads();
        *(short8*)(&Ah[sdst]) = *(short8*)h;
        *(short8*)(&Al[sdst]) = *(short8*)l;
        __syncthreads();
        short8 afh = *(short8*)(&Ah[(wave * 64 + lane) * 8]);
        short8 afl = *(short8*)(&Al[(wave * 64 + lane) * 8]);
        #pragma unroll
        for (int nt = 0; nt < NT; ++nt) {
            size_t bi = ((size_t)(nt * KT + kt) * 64 + lane);
            short8 bfh = ((const short8*)Bh)[bi];
            short8 bfl = ((const short8*)Bl)[bi];
            acc[nt] = __builtin_amdgcn_mfma_f32_16x16x32_bf16(afh, bfh, acc[nt], 0, 0, 0);
            acc[nt] = __builtin_amdgcn_mfma_f32_16x16x32_bf16(afh, bfl, acc[nt], 0, 0, 0);
            acc[nt] = __builtin_amdgcn_mfma_f32_16x16x32_bf16(afl, bfh, acc[nt], 0, 0, 0);
        }
    }

    size_t rbase = row0 + wave * 16 + quad * 4;
    if (!ACT) {
        float4 d4 = *(const float4*)(dis + rbase);
        float dr[4] = {d4.x, d4.y, d4.z, d4.w};
        #pragma unroll
        for (int nt = 0; nt < NT; ++nt)
            #pragma unroll
            for (int r = 0; r < 4; ++r)
                Cout[(rbase + r) * N + nt * 16 + col] = (_Float16)(acc[nt][r] * dr[r]);
    } else {
        float bv[NT];
        #pragma unroll
        for (int nt = 0; nt < NT; ++nt) bv[nt] = bias[nt * 16 + col];
        float mr[4] = {0.f, 0.f, 0.f, 0.f};
        #pragma unroll
        for (int nt = 0; nt < NT; ++nt)
            #pragma unroll
            for (int r = 0; r < 4; ++r) {
                float v = fmaxf(acc[nt][r] + bv[nt], 0.0f);
                acc[nt][r] = v;
                mr[r] = fmaxf(mr[r], v);
            }
        #pragma unroll
        for (int mask = 1; mask < 16; mask <<= 1)
            #pragma unroll
            for (int r = 0; r < 4; ++r) mr[r] = fmaxf(mr[r], __shfl_xor(mr[r], mask, 64));
        float sr[4] = {0.f, 0.f, 0.f, 0.f};
        #pragma unroll
        for (int nt = 0; nt < NT; ++nt)
            #pragma unroll
            for (int r = 0; r < 4; ++r) {
                float t = __expf(acc[nt][r] - mr[r]);
                acc[nt][r] = t;
                sr[r] += t;
            }
        #pragma unroll
        for (int mask = 1; mask < 16; mask <<= 1)
            #pragma unroll
            for (int r = 0; r < 4; ++r) sr[r] += __shfl_xor(sr[r], mask, 64);
        float inv[4];
        #pragma unroll
        for (int r = 0; r < 4; ++r) inv[r] = 1.0f / sr[r];
        #pragma unroll
        for (int nt = 0; nt < NT; ++nt)
            #pragma unroll
            for (int r = 0; r < 4; ++r)
                Cout[(rbase + r) * N + nt * 16 + col] = (_Float16)(acc[nt][r] * inv[r]);
    }
}

// ---------------- aggregation, DOUT=128, fp16 rows: quarter-wave (16 lanes x 16B) per edge ----------------

template <bool ACT>
__global__ __launch_bounds__(256) void k_agg128h(const _Float16* __restrict__ h, const int* __restrict__ off,
                                                 const ushort_t* __restrict__ ss, const float* __restrict__ dis,
                                                 const float* __restrict__ bias, _Float16* __restrict__ out) {
    int lane = threadIdx.x & 63;
    int sub = lane >> 4;      // 0..3: edge slot
    int li  = lane & 15;      // column group: halfs [li*8, li*8+8)
    int c0  = li * 8;
    int n = blockIdx.x * 4 + (threadIdx.x >> 6);
    int e0 = off[n], e1 = off[n + 1];
    int e = e0;
    float acc[8];
    #pragma unroll
    for (int j = 0; j < 8; ++j) acc[j] = 0.0f;

    if (ACT) {
        half8 hacc = {0, 0, 0, 0, 0, 0, 0, 0};
        for (; e + 16 <= e1; e += 16) {
            int s0 = ss[e + sub];
            int s1 = ss[e + 4 + sub];
            int s2 = ss[e + 8 + sub];
            int s3 = ss[e + 12 + sub];
            half8 v0 = *(const half8*)(h + (size_t)s0 * 128 + c0);
            half8 v1 = *(const half8*)(h + (size_t)s1 * 128 + c0);
            half8 v2 = *(const half8*)(h + (size_t)s2 * 128 + c0);
            half8 v3 = *(const half8*)(h + (size_t)s3 * 128 + c0);
            hacc += (v0 + v1) + (v2 + v3);
        }
        for (; e + 8 <= e1; e += 8) {
            int sa = ss[e + sub];
            int sb = ss[e + 4 + sub];
            half8 va = *(const half8*)(h + (size_t)sa * 128 + c0);
            half8 vb = *(const half8*)(h + (size_t)sb * 128 + c0);
            hacc += va + vb;
        }
        #pragma unroll
        for (int j = 0; j < 8; ++j) acc[j] = (float)hacc[j];
    } else {
        for (; e + 16 <= e1; e += 16) {
            int s0 = ss[e + sub];
            int s1 = ss[e + 4 + sub];
            int s2 = ss[e + 8 + sub];
            int s3 = ss[e + 12 + sub];
            half8 v0 = *(const half8*)(h + (size_t)s0 * 128 + c0);
            half8 v1 = *(const half8*)(h + (size_t)s1 * 128 + c0);
            half8 v2 = *(const half8*)(h + (size_t)s2 * 128 + c0);
            half8 v3 = *(const half8*)(h + (size_t)s3 * 128 + c0);
            half8 vs = (v0 + v1) + (v2 + v3);
            #pragma unroll
            for (int j = 0; j < 8; ++j) acc[j] += (float)vs[j];
        }
        for (; e + 8 <= e1; e += 8) {
            int sa = ss[e + sub];
            int sb = ss[e + 4 + sub];
            half8 va = *(const half8*)(h + (size_t)sa * 128 + c0);
            half8 vb = *(const half8*)(h + (size_t)sb * 128 + c0);
            half8 vs = va + vb;
            #pragma unroll
            for (int j = 0; j < 8; ++j) acc[j] += (float)vs[j];
        }
    }
    while (e < e1) {
        int rem = e1 - e;
        int idx = e + sub;
        if (idx >= e1) idx = e1 - 1;
        int s = ss[idx];
        half8 v = *(const half8*)(h + (size_t)s * 128 + c0);
        float w = (sub < rem) ? 1.0f : 0.0f;
        #pragma unroll
        for (int j = 0; j < 8; ++j) acc[j] = fmaf(w, (float)v[j], acc[j]);
        e += 4;
    }

    #pragma unroll
    for (int mask = 32; mask >= 16; mask >>= 1)
        #pragma unroll
        for (int j = 0; j < 8; ++j) acc[j] += __shfl_xor(acc[j], mask, 64);

    float dn = dis[n];
    if (ACT) {
        float m = 0.0f;
        #pragma unroll
        for (int j = 0; j < 8; ++j) {
            float v = fmaxf(fmaf(acc[j], dn, bias[c0 + j]), 0.0f);
            acc[j] = v;
            m = fmaxf(m, v);
        }
        #pragma unroll
        for (int mask = 8; mask > 0; mask >>= 1) m = fmaxf(m, __shfl_xor(m, mask, 64));
        float sum = 0.0f;
        #pragma unroll
        for (int j = 0; j < 8; ++j) {
            float t = __expf(acc[j] - m);
            acc[j] = t;
            sum += t;
        }
        #pragma unroll
        for (int mask = 8; mask > 0; mask >>= 1) sum += __shfl_xor(sum, mask, 64);
        float inv = 1.0f / sum;
        #pragma unroll
        for (int j = 0; j < 8; ++j) acc[j] *= inv;
    } else {
        #pragma unroll
        for (int j = 0; j < 8; ++j) acc[j] *= dn;
    }
    if (sub == 0) {
        half8 o;
        #pragma unroll
        for (int j = 0; j < 8; ++j) o[j] = (_Float16)acc[j];
        *(half8*)(out + (size_t)n * 128 + c0) = o;
    }
}

// ---------------- aggregation, DOUT=64, fp16 rows: eighth-wave (8 lanes x 16B) per edge ----------------

__global__ __launch_bounds__(256) void k_agg64h(const _Float16* __restrict__ h, const int* __restrict__ off,
                                                const ushort_t* __restrict__ ss, const float* __restrict__ dis,
                                                const float* __restrict__ bias, float* __restrict__ out) {
    int lane = threadIdx.x & 63;
    int sub = lane >> 3;      // 0..7: edge slot
    int li  = lane & 7;       // column group: halfs [li*8, li*8+8)
    int c0  = li * 8;
    int n = blockIdx.x * 4 + (threadIdx.x >> 6);
    int e0 = off[n], e1 = off[n + 1];
    int e = e0;
    float acc[8];
    #pragma unroll
    for (int j = 0; j < 8; ++j) acc[j] = 0.0f;

    half8 hacc = {0, 0, 0, 0, 0, 0, 0, 0};
    for (; e + 16 <= e1; e += 16) {
        int s0 = ss[e + sub];
        int s1 = ss[e + 8 + sub];
        half8 v0 = *(const half8*)(h + (size_t)s0 * 64 + c0);
        half8 v1 = *(const half8*)(h + (size_t)s1 * 64 + c0);
        hacc += v0 + v1;
    }
    for (; e + 8 <= e1; e += 8) {
        int s = ss[e + sub];
        half8 v = *(const half8*)(h + (size_t)s * 64 + c0);
        hacc += v;
    }
    #pragma unroll
    for (int j = 0; j < 8; ++j) acc[j] = (float)hacc[j];

    int rem = e1 - e;
    if (rem > 0) {
        int idx = e + sub;
        if (idx >= e1) idx = e1 - 1;
        int s = ss[idx];
        half8 v = *(const half8*)(h + (size_t)s * 64 + c0);
        float w = (sub < rem) ? 1.0f : 0.0f;
        #pragma unroll
        for (int j = 0; j < 8; ++j) acc[j] = fmaf(w, (float)v[j], acc[j]);
    }

    #pragma unroll
    for (int mask = 32; mask >= 8; mask >>= 1)
        #pragma unroll
        for (int j = 0; j < 8; ++j) acc[j] += __shfl_xor(acc[j], mask, 64);

    float dn = dis[n];
    float m = 0.0f;
    #pragma unroll
    for (int j = 0; j < 8; ++j) {
        float v = fmaxf(fmaf(acc[j], dn, bias[c0 + j]), 0.0f);
        acc[j] = v;
        m = fmaxf(m, v);
    }
    #pragma unroll
    for (int mask = 4; mask > 0; mask >>= 1) m = fmaxf(m, __shfl_xor(m, mask, 64));
    float sum = 0.0f;
    #pragma unroll
    for (int j = 0; j < 8; ++j) {
        float t = __expf(acc[j] - m);
        acc[j] = t;
        sum += t;
    }
    #pragma unroll
    for (int mask = 4; mask > 0; mask >>= 1) sum += __shfl_xor(sum, mask, 64);
    float inv = 1.0f / sum;
    if (sub == 0) {
        float* op = out + (size_t)n * 64 + c0;
        *(float4*)(op)     = make_float4(acc[0] * inv, acc[1] * inv, acc[2] * inv, acc[3] * inv);
        *(float4*)(op + 4) = make_float4(acc[4] * inv, acc[5] * inv, acc[6] * inv, acc[7] * inv);
    }
}

// ---------------- launch ----------------

extern "C" void kernel_launch(void* const* d_in, const int* in_sizes, int n_in,
                              void* d_out, int out_size, void* d_ws, size_t ws_size,
                              hipStream_t stream) {
    const float* x  = (const float*)d_in[0];
    const int*   ei = (const int*)d_in[1];
    const float* W1 = (const float*)d_in[2];
    const float* b1 = (const float*)d_in[3];
    const float* W2 = (const float*)d_in[4];
    const float* b2 = (const float*)d_in[5];
    const float* W3 = (const float*)d_in[6];
    const float* b3 = (const float*)d_in[7];
    const int* srcE = ei;
    const int* dstE = ei + N_EDGES;

    char* p = (char*)d_ws;
    auto carve = [&](size_t bytes) {
        char* q = p;
        p += (bytes + 255) & ~(size_t)255;
        return q;
    };
    int*          gcur  = (int*)carve(sizeof(int) * 256);
    int*          boff  = (int*)carve(sizeof(int) * 257);
    int*          off   = (int*)carve(sizeof(int) * (N_NODES + 1));
    float*        dis   = (float*)carve(sizeof(float) * N_NODES);
    unsigned*     pk    = (unsigned*)carve(sizeof(unsigned) * 256 * CAP);
    ushort_t*     ssort = (ushort_t*)carve(sizeof(ushort_t) * E_TOT);
    short*        w1h   = (short*)carve(sizeof(short) * 128 * 256);
    short*        w1l   = (short*)carve(sizeof(short) * 128 * 256);
    short*        w2h   = (short*)carve(sizeof(short) * 256 * 128);
    short*        w2l   = (short*)carve(sizeof(short) * 256 * 128);
    short*        w3h   = (short*)carve(sizeof(short) * 128 * 64);
    short*        w3l   = (short*)carve(sizeof(short) * 128 * 64);
    _Float16*     xh    = (_Float16*)carve(sizeof(_Float16) * (size_t)N_NODES * 128);
    _Float16*     a0h   = (_Float16*)carve(sizeof(_Float16) * (size_t)N_NODES * 128);
    _Float16*     x1h   = (_Float16*)carve(sizeof(_Float16) * (size_t)N_NODES * 256);
    _Float16*     x2h   = (_Float16*)carve(sizeof(_Float16) * (size_t)N_NODES * 128);
    _Float16*     hh    = (_Float16*)carve(sizeof(_Float16) * (size_t)N_NODES * 128);  // h2' then h3'

    (void)hipMemsetAsync(gcur, 0, sizeof(int) * 256, stream);
    k_bucket<<<256, 1024, 0, stream>>>(srcE, dstE, gcur, pk);
    k_boff<<<1, 256, 0, stream>>>(gcur, boff, off);
    k_sortb<<<256, 1024, 0, stream>>>(pk, gcur, boff, off, dis, ssort);
    k_fused<<<NBX + NBW, 256, 0, stream>>>(x, dis, xh, W1, w1h, w1l, W2, w2h, w2l, W3, w3h, w3l);

    // layer 1 (agg-first): a0[n] = dis[n] * sum xh[src]  (xh pre-scaled by dis[src]), fp16
    k_agg128h<false><<<N_NODES / 4, 256, 0, stream>>>(xh, off, ssort, dis, nullptr, a0h);
    // x1 = softmax(relu(a0@W1 + b1)), fp16
    k_mm<128, 256, true><<<N_NODES / 64, 256, 0, stream>>>(a0h, w1h, w1l, b1, nullptr, x1h);
    // layer 2: h2' = fp16(dis .* (x1@W2)); x2 = softmax(relu(dis[n]*segsum(h2') + b2)), fp16
    k_mm<256, 128, false><<<N_NODES / 64, 256, 0, stream>>>(x1h, w2h, w2l, nullptr, dis, hh);
    k_agg128h<true><<<N_NODES / 4, 256, 0, stream>>>(hh, off, ssort, dis, b2, x2h);
    // layer 3: h3' = fp16(dis .* (x2@W3)); out = softmax(relu(dis[n]*segsum(h3') + b3)), fp32
    k_mm<128, 64, false><<<N_NODES / 64, 256, 0, stream>>>(x2h, w3h, w3l, nullptr, dis, hh);
    k_agg64h<<<N_NODES / 4, 256, 0, stream>>>(hh, off, ssort, dis, b3, (float*)d_out);
}

// Round 17
// 293.629 us; speedup vs baseline: 1.2477x; 1.0884x over previous
//
#include <hip/hip_runtime.h>
#include <cstdint>
#include <cstddef>

#define N_NODES 65536
#define N_EDGES 1048576
#define E_TOT   (N_EDGES + N_NODES)
#define CAP     5120   // bucket region capacity (mean 4096, +16 sigma)

using short8  = __attribute__((ext_vector_type(8))) short;
using floatx4 = __attribute__((ext_vector_type(4))) float;
using half8   = __attribute__((ext_vector_type(8))) _Float16;
using half4   = __attribute__((ext_vector_type(4))) _Float16;
typedef unsigned short ushort_t;

// split fp32 -> bf16 hi (RTN) + bf16 lo (trunc of residual)
__device__ inline void split_bf16(float a, short& hi, short& lo) {
    unsigned u  = __float_as_uint(a);
    unsigned hr = (u + 0x7fffu + ((u >> 16) & 1u)) >> 16;
    float    hf = __uint_as_float(hr << 16);
    hi = (short)hr;
    float    lf = a - hf;
    lo = (short)(__float_as_uint(lf) >> 16);
}

// ---------------- preprocessing: bucket counting sort ----------------

__global__ __launch_bounds__(1024) void k_bucket(const int* __restrict__ src, const int* __restrict__ dst,
                                                 int* __restrict__ gcur, unsigned* __restrict__ pk) {
    __shared__ int cnt[256];
    __shared__ int cur[256];
    int tid = threadIdx.x;
    if (tid < 256) cnt[tid] = 0;
    __syncthreads();
    int base = blockIdx.x * 4096;
    #pragma unroll
    for (int j = 0; j < 4; ++j) {
        int d = __builtin_nontemporal_load(&dst[base + j * 1024 + tid]);
        atomicAdd(&cnt[d >> 8], 1);
    }
    __syncthreads();
    if (tid < 256) cur[tid] = CAP * tid + atomicAdd(&gcur[tid], cnt[tid]);
    __syncthreads();
    #pragma unroll
    for (int j = 0; j < 4; ++j) {
        int e = base + j * 1024 + tid;
        int d = __builtin_nontemporal_load(&dst[e]);
        int s = __builtin_nontemporal_load(&src[e]);
        int pos = atomicAdd(&cur[d >> 8], 1);
        pk[pos] = ((unsigned)s << 16) | (unsigned)d;
    }
}

__global__ __launch_bounds__(256) void k_boff(const int* __restrict__ gcur, int* __restrict__ boff,
                                              int* __restrict__ off) {
    __shared__ int sb[256];
    int tid = threadIdx.x;
    int v = gcur[tid] + 256;     // edges + one self loop per dst
    sb[tid] = v;
    __syncthreads();
    #pragma unroll
    for (int s = 1; s < 256; s <<= 1) {
        int t = (tid >= s) ? sb[tid - s] : 0;
        __syncthreads();
        sb[tid] += t;
        __syncthreads();
    }
    boff[tid] = sb[tid] - v;
    if (tid == 255) boff[256] = sb[255];
    if (tid == 0) off[N_NODES] = E_TOT;
}

__global__ __launch_bounds__(1024) void k_sortb(const unsigned* __restrict__ pk, const int* __restrict__ gcur,
                                                const int* __restrict__ boff, int* __restrict__ off,
                                                float* __restrict__ dis, ushort_t* __restrict__ ssort) {
    __shared__ int cnt[256];
    __shared__ int sb[256];
    __shared__ int cur[256];
    int b = blockIdx.x;
    int tid = threadIdx.x;
    int n = gcur[b];
    const unsigned* p = pk + (size_t)b * CAP;
    if (tid < 256) cnt[tid] = 0;
    __syncthreads();
    for (int i = tid; i < n; i += 1024) atomicAdd(&cnt[p[i] & 255u], 1);
    __syncthreads();
    if (tid < 256) sb[tid] = cnt[tid];
    __syncthreads();
    #pragma unroll
    for (int s = 1; s < 256; s <<= 1) {
        int t = (tid < 256 && tid >= s) ? sb[tid - s] : 0;
        __syncthreads();
        if (tid < 256) sb[tid] += t;
        __syncthreads();
    }
    if (tid < 256) {
        int deg = cnt[tid];
        int o = boff[b] + (sb[tid] - deg) + tid;
        int d = b * 256 + tid;
        off[d] = o;
        dis[d] = rsqrtf((float)(deg + 1));
        ssort[o + deg] = (ushort_t)d;
        cur[tid] = o;
    }
    __syncthreads();
    for (int i = tid; i < n; i += 1024) {
        unsigned v = p[i];
        int pos = atomicAdd(&cur[v & 255u], 1);
        ssort[pos] = (ushort_t)(v >> 16);
    }
}

// ---------------- fused: convx + W1 (bf16 hi/lo) + W2,W3 (fp16) fragment conversion ----------------

#define G1 (16 * 4 * 64)   // W1 128x256
#define G2 (8 * 8 * 64)    // W2 256x128
#define G3 (4 * 4 * 64)    // W3 128x64
#define NBX 8192           // convx blocks
#define NBW ((G1 + G2 + G3 + 255) / 256)

__device__ inline void convw_split(const float* W, int K, int N, short* Bh, short* Bl, int g) {
    int lane = g & 63;
    int kt = (g >> 6) % (K / 32);
    int nt = (g >> 6) / (K / 32);
    int n = nt * 16 + (lane & 15);
    int kbase = kt * 32 + (lane >> 4) * 8;
    #pragma unroll
    for (int j = 0; j < 8; ++j) {
        short h, l;
        split_bf16(W[(size_t)(kbase + j) * N + n], h, l);
        Bh[(size_t)g * 8 + j] = h;
        Bl[(size_t)g * 8 + j] = l;
    }
}

__device__ inline void convw_h(const float* W, int K, int N, _Float16* Bf, int g) {
    int lane = g & 63;
    int kt = (g >> 6) % (K / 32);
    int nt = (g >> 6) / (K / 32);
    int n = nt * 16 + (lane & 15);
    int kbase = kt * 32 + (lane >> 4) * 8;
    #pragma unroll
    for (int j = 0; j < 8; ++j)
        Bf[(size_t)g * 8 + j] = (_Float16)W[(size_t)(kbase + j) * N + n];
}

__global__ __launch_bounds__(256) void k_fused(
        const float* __restrict__ x, const float* __restrict__ dis, _Float16* __restrict__ xh,
        const float* __restrict__ W1, short* __restrict__ w1h, short* __restrict__ w1l,
        const float* __restrict__ W2, _Float16* __restrict__ w2f,
        const float* __restrict__ W3, _Float16* __restrict__ w3f) {
    int b = blockIdx.x;
    if (b < NBX) {
        int idx = (b * 256 + threadIdx.x) * 4;
        int row = idx >> 7;
        float d = dis[row];
        float4 v = *(const float4*)(x + idx);
        half4 o = {(_Float16)(d * v.x), (_Float16)(d * v.y), (_Float16)(d * v.z), (_Float16)(d * v.w)};
        *(half4*)(xh + idx) = o;
    } else {
        int g = (b - NBX) * 256 + threadIdx.x;
        if (g < G1)                 convw_split(W1, 128, 256, w1h, w1l, g);
        else if (g < G1 + G2)       convw_h(W2, 256, 128, w2f, g - G1);
        else if (g < G1 + G2 + G3)  convw_h(W3, 128, 64, w3f, g - G1 - G2);
    }
}

// ---------------- GEMM, split-bf16 path (layer 1): no LDS, no barriers ----------------
// Each lane loads its A fragment (16B) directly from global, splits in-register.
// Epilogue: C = softmax(relu(C + bias)) -> fp16.

template <int K, int N>
__global__ __launch_bounds__(256) void k_mms(const _Float16* __restrict__ A,
                                             const short* __restrict__ Bh, const short* __restrict__ Bl,
                                             const float* __restrict__ bias, _Float16* __restrict__ Cout) {
    constexpr int NT = N / 16;
    constexpr int KT = K / 32;
    int tid = threadIdx.x;
    int wave = tid >> 6, lane = tid & 63;
    int quad = lane >> 4, col = lane & 15;
    size_t row0 = (size_t)blockIdx.x * 64;
    const _Float16* ap = A + (row0 + wave * 16 + col) * K + quad * 8;

    floatx4 acc[NT];
    #pragma unroll
    for (int t = 0; t < NT; ++t) acc[t] = (floatx4)0.0f;

    for (int kt = 0; kt < KT; ++kt) {
        half8 a8 = *(const half8*)(ap + kt * 32);
        short ah[8], al[8];
        #pragma unroll
        for (int j = 0; j < 8; ++j) split_bf16((float)a8[j], ah[j], al[j]);
        short8 afh = *(short8*)ah;
        short8 afl = *(short8*)al;
        #pragma unroll
        for (int nt = 0; nt < NT; ++nt) {
            size_t bi = ((size_t)(nt * KT + kt) * 64 + lane);
            short8 bfh = ((const short8*)Bh)[bi];
            short8 bfl = ((const short8*)Bl)[bi];
            acc[nt] = __builtin_amdgcn_mfma_f32_16x16x32_bf16(afh, bfh, acc[nt], 0, 0, 0);
            acc[nt] = __builtin_amdgcn_mfma_f32_16x16x32_bf16(afh, bfl, acc[nt], 0, 0, 0);
            acc[nt] = __builtin_amdgcn_mfma_f32_16x16x32_bf16(afl, bfh, acc[nt], 0, 0, 0);
        }
    }

    size_t rbase = row0 + wave * 16 + quad * 4;
    float bv[NT];
    #pragma unroll
    for (int nt = 0; nt < NT; ++nt) bv[nt] = bias[nt * 16 + col];
    float mr[4] = {0.f, 0.f, 0.f, 0.f};
    #pragma unroll
    for (int nt = 0; nt < NT; ++nt)
        #pragma unroll
        for (int r = 0; r < 4; ++r) {
            float v = fmaxf(acc[nt][r] + bv[nt], 0.0f);
            acc[nt][r] = v;
            mr[r] = fmaxf(mr[r], v);
        }
    #pragma unroll
    for (int mask = 1; mask < 16; mask <<= 1)
        #pragma unroll
        for (int r = 0; r < 4; ++r) mr[r] = fmaxf(mr[r], __shfl_xor(mr[r], mask, 64));
    float sr[4] = {0.f, 0.f, 0.f, 0.f};
    #pragma unroll
    for (int nt = 0; nt < NT; ++nt)
        #pragma unroll
        for (int r = 0; r < 4; ++r) {
            float t = __expf(acc[nt][r] - mr[r]);
            acc[nt][r] = t;
            sr[r] += t;
        }
    #pragma unroll
    for (int mask = 1; mask < 16; mask <<= 1)
        #pragma unroll
        for (int r = 0; r < 4; ++r) sr[r] += __shfl_xor(sr[r], mask, 64);
    float inv[4];
    #pragma unroll
    for (int r = 0; r < 4; ++r) inv[r] = 1.0f / sr[r];
    #pragma unroll
    for (int nt = 0; nt < NT; ++nt)
        #pragma unroll
        for (int r = 0; r < 4; ++r)
            Cout[(rbase + r) * N + nt * 16 + col] = (_Float16)(acc[nt][r] * inv[r]);
}

// ---------------- GEMM, fp16 path (layers 2/3): single f16 MFMA, no LDS, no barriers ----------------
// Epilogue: C = dis[row] * C -> fp16 (feeds the gather).

template <int K, int N>
__global__ __launch_bounds__(256) void k_mmh(const _Float16* __restrict__ A,
                                             const _Float16* __restrict__ Bf,
                                             const float* __restrict__ dis, _Float16* __restrict__ Cout) {
    constexpr int NT = N / 16;
    constexpr int KT = K / 32;
    int tid = threadIdx.x;
    int wave = tid >> 6, lane = tid & 63;
    int quad = lane >> 4, col = lane & 15;
    size_t row0 = (size_t)blockIdx.x * 64;
    const _Float16* ap = A + (row0 + wave * 16 + col) * K + quad * 8;

    floatx4 acc[NT];
    #pragma unroll
    for (int t = 0; t < NT; ++t) acc[t] = (floatx4)0.0f;

    for (int kt = 0; kt < KT; ++kt) {
        half8 a8 = *(const half8*)(ap + kt * 32);
        #pragma unroll
        for (int nt = 0; nt < NT; ++nt) {
            half8 bf = ((const half8*)Bf)[(size_t)(nt * KT + kt) * 64 + lane];
            acc[nt] = __builtin_amdgcn_mfma_f32_16x16x32_f16(a8, bf, acc[nt], 0, 0, 0);
        }
    }

    size_t rbase = row0 + wave * 16 + quad * 4;
    float4 d4 = *(const float4*)(dis + rbase);
    float dr[4] = {d4.x, d4.y, d4.z, d4.w};
    #pragma unroll
    for (int nt = 0; nt < NT; ++nt)
        #pragma unroll
        for (int r = 0; r < 4; ++r)
            Cout[(rbase + r) * N + nt * 16 + col] = (_Float16)(acc[nt][r] * dr[r]);
}

// ---------------- aggregation, DOUT=128, fp16 rows: quarter-wave (16 lanes x 16B) per edge ----------------

template <bool ACT>
__global__ __launch_bounds__(256) void k_agg128h(const _Float16* __restrict__ h, const int* __restrict__ off,
                                                 const ushort_t* __restrict__ ss, const float* __restrict__ dis,
                                                 const float* __restrict__ bias, _Float16* __restrict__ out) {
    int lane = threadIdx.x & 63;
    int sub = lane >> 4;
    int li  = lane & 15;
    int c0  = li * 8;
    int n = blockIdx.x * 4 + (threadIdx.x >> 6);
    int e0 = off[n], e1 = off[n + 1];
    int e = e0;
    float acc[8];
    #pragma unroll
    for (int j = 0; j < 8; ++j) acc[j] = 0.0f;

    if (ACT) {
        half8 hacc = {0, 0, 0, 0, 0, 0, 0, 0};
        for (; e + 16 <= e1; e += 16) {
            int s0 = ss[e + sub];
            int s1 = ss[e + 4 + sub];
            int s2 = ss[e + 8 + sub];
            int s3 = ss[e + 12 + sub];
            half8 v0 = *(const half8*)(h + (size_t)s0 * 128 + c0);
            half8 v1 = *(const half8*)(h + (size_t)s1 * 128 + c0);
            half8 v2 = *(const half8*)(h + (size_t)s2 * 128 + c0);
            half8 v3 = *(const half8*)(h + (size_t)s3 * 128 + c0);
            hacc += (v0 + v1) + (v2 + v3);
        }
        for (; e + 8 <= e1; e += 8) {
            int sa = ss[e + sub];
            int sb = ss[e + 4 + sub];
            half8 va = *(const half8*)(h + (size_t)sa * 128 + c0);
            half8 vb = *(const half8*)(h + (size_t)sb * 128 + c0);
            hacc += va + vb;
        }
        #pragma unroll
        for (int j = 0; j < 8; ++j) acc[j] = (float)hacc[j];
    } else {
        for (; e + 16 <= e1; e += 16) {
            int s0 = ss[e + sub];
            int s1 = ss[e + 4 + sub];
            int s2 = ss[e + 8 + sub];
            int s3 = ss[e + 12 + sub];
            half8 v0 = *(const half8*)(h + (size_t)s0 * 128 + c0);
            half8 v1 = *(const half8*)(h + (size_t)s1 * 128 + c0);
            half8 v2 = *(const half8*)(h + (size_t)s2 * 128 + c0);
            half8 v3 = *(const half8*)(h + (size_t)s3 * 128 + c0);
            half8 vs = (v0 + v1) + (v2 + v3);
            #pragma unroll
            for (int j = 0; j < 8; ++j) acc[j] += (float)vs[j];
        }
        for (; e + 8 <= e1; e += 8) {
            int sa = ss[e + sub];
            int sb = ss[e + 4 + sub];
            half8 va = *(const half8*)(h + (size_t)sa * 128 + c0);
            half8 vb = *(const half8*)(h + (size_t)sb * 128 + c0);
            half8 vs = va + vb;
            #pragma unroll
            for (int j = 0; j < 8; ++j) acc[j] += (float)vs[j];
        }
    }
    while (e < e1) {
        int rem = e1 - e;
        int idx = e + sub;
        if (idx >= e1) idx = e1 - 1;
        int s = ss[idx];
        half8 v = *(const half8*)(h + (size_t)s * 128 + c0);
        float w = (sub < rem) ? 1.0f : 0.0f;
        #pragma unroll
        for (int j = 0; j < 8; ++j) acc[j] = fmaf(w, (float)v[j], acc[j]);
        e += 4;
    }

    #pragma unroll
    for (int mask = 32; mask >= 16; mask >>= 1)
        #pragma unroll
        for (int j = 0; j < 8; ++j) acc[j] += __shfl_xor(acc[j], mask, 64);

    float dn = dis[n];
    if (ACT) {
        float m = 0.0f;
        #pragma unroll
        for (int j = 0; j < 8; ++j) {
            float v = fmaxf(fmaf(acc[j], dn, bias[c0 + j]), 0.0f);
            acc[j] = v;
            m = fmaxf(m, v);
        }
        #pragma unroll
        for (int mask = 8; mask > 0; mask >>= 1) m = fmaxf(m, __shfl_xor(m, mask, 64));
        float sum = 0.0f;
        #pragma unroll
        for (int j = 0; j < 8; ++j) {
            float t = __expf(acc[j] - m);
            acc[j] = t;
            sum += t;
        }
        #pragma unroll
        for (int mask = 8; mask > 0; mask >>= 1) sum += __shfl_xor(sum, mask, 64);
        float inv = 1.0f / sum;
        #pragma unroll
        for (int j = 0; j < 8; ++j) acc[j] *= inv;
    } else {
        #pragma unroll
        for (int j = 0; j < 8; ++j) acc[j] *= dn;
    }
    if (sub == 0) {
        half8 o;
        #pragma unroll
        for (int j = 0; j < 8; ++j) o[j] = (_Float16)acc[j];
        *(half8*)(out + (size_t)n * 128 + c0) = o;
    }
}

// ---------------- aggregation, DOUT=64, fp16 rows: eighth-wave (8 lanes x 16B) per edge ----------------

__global__ __launch_bounds__(256) void k_agg64h(const _Float16* __restrict__ h, const int* __restrict__ off,
                                                const ushort_t* __restrict__ ss, const float* __restrict__ dis,
                                                const float* __restrict__ bias, float* __restrict__ out) {
    int lane = threadIdx.x & 63;
    int sub = lane >> 3;
    int li  = lane & 7;
    int c0  = li * 8;
    int n = blockIdx.x * 4 + (threadIdx.x >> 6);
    int e0 = off[n], e1 = off[n + 1];
    int e = e0;
    float acc[8];
    #pragma unroll
    for (int j = 0; j < 8; ++j) acc[j] = 0.0f;

    half8 hacc = {0, 0, 0, 0, 0, 0, 0, 0};
    for (; e + 16 <= e1; e += 16) {
        int s0 = ss[e + sub];
        int s1 = ss[e + 8 + sub];
        half8 v0 = *(const half8*)(h + (size_t)s0 * 64 + c0);
        half8 v1 = *(const half8*)(h + (size_t)s1 * 64 + c0);
        hacc += v0 + v1;
    }
    for (; e + 8 <= e1; e += 8) {
        int s = ss[e + sub];
        half8 v = *(const half8*)(h + (size_t)s * 64 + c0);
        hacc += v;
    }
    #pragma unroll
    for (int j = 0; j < 8; ++j) acc[j] = (float)hacc[j];

    int rem = e1 - e;
    if (rem > 0) {
        int idx = e + sub;
        if (idx >= e1) idx = e1 - 1;
        int s = ss[idx];
        half8 v = *(const half8*)(h + (size_t)s * 64 + c0);
        float w = (sub < rem) ? 1.0f : 0.0f;
        #pragma unroll
        for (int j = 0; j < 8; ++j) acc[j] = fmaf(w, (float)v[j], acc[j]);
    }

    #pragma unroll
    for (int mask = 32; mask >= 8; mask >>= 1)
        #pragma unroll
        for (int j = 0; j < 8; ++j) acc[j] += __shfl_xor(acc[j], mask, 64);

    float dn = dis[n];
    float m = 0.0f;
    #pragma unroll
    for (int j = 0; j < 8; ++j) {
        float v = fmaxf(fmaf(acc[j], dn, bias[c0 + j]), 0.0f);
        acc[j] = v;
        m = fmaxf(m, v);
    }
    #pragma unroll
    for (int mask = 4; mask > 0; mask >>= 1) m = fmaxf(m, __shfl_xor(m, mask, 64));
    float sum = 0.0f;
    #pragma unroll
    for (int j = 0; j < 8; ++j) {
        float t = __expf(acc[j] - m);
        acc[j] = t;
        sum += t;
    }
    #pragma unroll
    for (int mask = 4; mask > 0; mask >>= 1) sum += __shfl_xor(sum, mask, 64);
    float inv = 1.0f / sum;
    if (sub == 0) {
        float* op = out + (size_t)n * 64 + c0;
        *(float4*)(op)     = make_float4(acc[0] * inv, acc[1] * inv, acc[2] * inv, acc[3] * inv);
        *(float4*)(op + 4) = make_float4(acc[4] * inv, acc[5] * inv, acc[6] * inv, acc[7] * inv);
    }
}

// ---------------- launch ----------------

extern "C" void kernel_launch(void* const* d_in, const int* in_sizes, int n_in,
                              void* d_out, int out_size, void* d_ws, size_t ws_size,
                              hipStream_t stream) {
    const float* x  = (const float*)d_in[0];
    const int*   ei = (const int*)d_in[1];
    const float* W1 = (const float*)d_in[2];
    const float* b1 = (const float*)d_in[3];
    const float* W2 = (const float*)d_in[4];
    const float* b2 = (const float*)d_in[5];
    const float* W3 = (const float*)d_in[6];
    const float* b3 = (const float*)d_in[7];
    const int* srcE = ei;
    const int* dstE = ei + N_EDGES;

    char* p = (char*)d_ws;
    auto carve = [&](size_t bytes) {
        char* q = p;
        p += (bytes + 255) & ~(size_t)255;
        return q;
    };
    int*          gcur  = (int*)carve(sizeof(int) * 256);
    int*          boff  = (int*)carve(sizeof(int) * 257);
    int*          off   = (int*)carve(sizeof(int) * (N_NODES + 1));
    float*        dis   = (float*)carve(sizeof(float) * N_NODES);
    unsigned*     pk    = (unsigned*)carve(sizeof(unsigned) * 256 * CAP);
    ushort_t*     ssort = (ushort_t*)carve(sizeof(ushort_t) * E_TOT);
    short*        w1h   = (short*)carve(sizeof(short) * 128 * 256);
    short*        w1l   = (short*)carve(sizeof(short) * 128 * 256);
    _Float16*     w2f   = (_Float16*)carve(sizeof(_Float16) * 256 * 128);
    _Float16*     w3f   = (_Float16*)carve(sizeof(_Float16) * 128 * 64);
    _Float16*     xh    = (_Float16*)carve(sizeof(_Float16) * (size_t)N_NODES * 128);
    _Float16*     a0h   = (_Float16*)carve(sizeof(_Float16) * (size_t)N_NODES * 128);
    _Float16*     x1h   = (_Float16*)carve(sizeof(_Float16) * (size_t)N_NODES * 256);
    _Float16*     x2h   = (_Float16*)carve(sizeof(_Float16) * (size_t)N_NODES * 128);
    _Float16*     hh    = (_Float16*)carve(sizeof(_Float16) * (size_t)N_NODES * 128);  // h2' then h3'

    (void)hipMemsetAsync(gcur, 0, sizeof(int) * 256, stream);
    k_bucket<<<256, 1024, 0, stream>>>(srcE, dstE, gcur, pk);
    k_boff<<<1, 256, 0, stream>>>(gcur, boff, off);
    k_sortb<<<256, 1024, 0, stream>>>(pk, gcur, boff, off, dis, ssort);
    k_fused<<<NBX + NBW, 256, 0, stream>>>(x, dis, xh, W1, w1h, w1l, W2, w2f, W3, w3f);

    // layer 1 (agg-first): a0[n] = dis[n] * sum xh[src], fp16
    k_agg128h<false><<<N_NODES / 4, 256, 0, stream>>>(xh, off, ssort, dis, nullptr, a0h);
    // x1 = softmax(relu(a0@W1 + b1)), fp16 (split-bf16 MFMA, error-critical)
    k_mms<128, 256><<<N_NODES / 64, 256, 0, stream>>>(a0h, w1h, w1l, b1, x1h);
    // layer 2: h2' = fp16(dis .* (x1@W2)) via fp16 MFMA; x2 = softmax(relu(dis[n]*segsum(h2') + b2))
    k_mmh<256, 128><<<N_NODES / 64, 256, 0, stream>>>(x1h, w2f, dis, hh);
    k_agg128h<true><<<N_NODES / 4, 256, 0, stream>>>(hh, off, ssort, dis, b2, x2h);
    // layer 3: h3' = fp16(dis .* (x2@W3)) via fp16 MFMA; out = softmax(relu(dis[n]*segsum(h3') + b3))
    k_mmh<128, 64><<<N_NODES / 64, 256, 0, stream>>>(x2h, w3f, dis, hh);
    k_agg64h<<<N_NODES / 4, 256, 0, stream>>>(hh, off, ssort, dis, b3, (float*)d_out);
}